// Round 6
// baseline (455.883 us; speedup 1.0000x reference)
//
#include <hip/hip_runtime.h>
#include <hip/hip_bf16.h>

#define N_NODES   10000
#define N_EDGES   320000
#define DIM       256
#define EDGE_DIM  64
#define FF_HIDDEN 512
#define GAMMA     0.5f

typedef __attribute__((ext_vector_type(8))) short bf16x8;
typedef __attribute__((ext_vector_type(4))) float f32x4;

static __device__ __forceinline__ unsigned short f2b(float f)
{
    union { __hip_bfloat16 b; unsigned short u; } c;
    c.b = __float2bfloat16(f);
    return c.u;
}
static __device__ __forceinline__ float b2f(unsigned short u)
{
    union { unsigned u32; float f; } c;
    c.u32 = ((unsigned)u) << 16;
    return c.f;
}

// Build one bf16x8 A-fragment from 8 consecutive f32 (32B), optional relu.
template <bool RELU>
static __device__ __forceinline__ bf16x8 load_a_frag(const float* __restrict__ p)
{
    float4 f0 = *(const float4*)p;
    float4 f1 = *(const float4*)(p + 4);
    if (RELU) {
        f0.x = fmaxf(f0.x, 0.f); f0.y = fmaxf(f0.y, 0.f);
        f0.z = fmaxf(f0.z, 0.f); f0.w = fmaxf(f0.w, 0.f);
        f1.x = fmaxf(f1.x, 0.f); f1.y = fmaxf(f1.y, 0.f);
        f1.z = fmaxf(f1.z, 0.f); f1.w = fmaxf(f1.w, 0.f);
    }
    bf16x8 r;
    r[0] = (short)f2b(f0.x); r[1] = (short)f2b(f0.y);
    r[2] = (short)f2b(f0.z); r[3] = (short)f2b(f0.w);
    r[4] = (short)f2b(f1.x); r[5] = (short)f2b(f1.y);
    r[6] = (short)f2b(f1.z); r[7] = (short)f2b(f1.w);
    return r;
}

// ---------------------------------------------------------------------------
// Edge-index dtype probe.
__global__ __launch_bounds__(256) void detect_kernel(const unsigned* __restrict__ ei,
                                                     int* __restrict__ flag)
{
    __shared__ int bad;
    if (threadIdx.x == 0) bad = 0;
    __syncthreads();
    int b = 0;
    for (int i = threadIdx.x; i < 1024; i += 256)
        if (ei[2 * i + 1] != 0u) b = 1;
    if (b) atomicAdd(&bad, 1);
    __syncthreads();
    if (threadIdx.x == 0) *flag = (bad == 0) ? 1 : 0;
}

__global__ __launch_bounds__(256) void convert_kernel(const unsigned* __restrict__ ei,
                                                      const int* __restrict__ flag,
                                                      int* __restrict__ src, int* __restrict__ dst,
                                                      int* __restrict__ counts)
{
    const int i = blockIdx.x * 256 + threadIdx.x;
    if (i >= N_EDGES) return;
    const int f = *flag;
    int s, d;
    if (f) { s = (int)ei[2 * i]; d = (int)ei[2 * (N_EDGES + i)]; }
    else   { s = (int)ei[i];     d = (int)ei[N_EDGES + i]; }
    src[i] = s;
    dst[i] = d;
    atomicAdd(&counts[d], 1);
}

__global__ __launch_bounds__(256) void scan_kernel(const int* __restrict__ counts,
                                                   int* __restrict__ row_start)
{
    __shared__ int lds[256];
    const int t = threadIdx.x;
    int vals[40];
    int tot = 0;
    const int base = t * 40;
#pragma unroll
    for (int j = 0; j < 40; ++j) {
        const int idx = base + j;
        const int c = (idx < N_NODES) ? counts[idx] : 0;
        vals[j] = tot;
        tot += c;
    }
    lds[t] = tot;
    __syncthreads();
    for (int off = 1; off < 256; off <<= 1) {
        const int tmp = (t >= off) ? lds[t - off] : 0;
        __syncthreads();
        lds[t] += tmp;
        __syncthreads();
    }
    const int ebase = lds[t] - tot;
#pragma unroll
    for (int j = 0; j < 40; ++j) {
        const int idx = base + j;
        if (idx < N_NODES) row_start[idx] = ebase + vals[j];
    }
    if (t == 0) row_start[N_NODES] = N_EDGES;
}

// Records perm[edge] = CSR slot so e can be written pre-permuted.
__global__ __launch_bounds__(256) void fill_kernel(const int* __restrict__ src,
                                                   const int* __restrict__ dst,
                                                   const int* __restrict__ row_start,
                                                   int* __restrict__ fillc,
                                                   int* __restrict__ perm,
                                                   int* __restrict__ csr_src)
{
    const int i = blockIdx.x * 256 + threadIdx.x;
    if (i >= N_EDGES) return;
    const int d = dst[i];
    const int pos = atomicAdd(&fillc[d], 1);
    const int slot = row_start[d] + pos;
    perm[i] = slot;
    csr_src[slot] = src[i];
}

// ---------------------------------------------------------------------------
// W[k][n] f32 -> wT[n][k] bf16
__global__ __launch_bounds__(256) void wconv_kernel(const float* __restrict__ W,
                                                    unsigned short* __restrict__ wT,
                                                    int K, int N)
{
    const int i = blockIdx.x * 256 + threadIdx.x;
    if (i >= K * N) return;
    const int k = i / N, n = i - k * N;
    wT[(size_t)n * K + k] = f2b(W[i]);
}

// ---------------------------------------------------------------------------
// Wave-level register GEMM (no LDS): out[M][N] f32 = A[M][K] @ W, wT=W^T bf16.
// Block = 1 wave; tile 64x64. grid = (ceil(M/64), N/64).
// Swapped-operand MFMA: mfma(bfrag, afrag) -> lane holds 4 consecutive n-cols
// at one m-row => direct float4 stores.
// MODE 0: plain. MODE 2: out = epi_x + relu(epi_a + acc).
template <int MODE, bool RELU_A>
__global__ __launch_bounds__(64) void wgemm_f32(const float* __restrict__ A,
                                                const unsigned short* __restrict__ wT,
                                                float* __restrict__ out,
                                                int M, int K, int N,
                                                const float* __restrict__ epi_a,
                                                const float* __restrict__ epi_x)
{
    const int lane = threadIdx.x;
    const int l15  = lane & 15;
    const int l4   = lane >> 4;          // 0..3
    const int m0   = blockIdx.x * 64;
    const int n0   = blockIdx.y * 64;

    f32x4 acc[4][4];
#pragma unroll
    for (int i = 0; i < 4; ++i)
#pragma unroll
        for (int j = 0; j < 4; ++j) acc[i][j] = f32x4{0.f, 0.f, 0.f, 0.f};

    int rowm[4];
#pragma unroll
    for (int i = 0; i < 4; ++i) rowm[i] = min(m0 + i * 16 + l15, M - 1);

    const int nk = K >> 6;
    for (int kt = 0; kt < nk; ++kt) {
        const int kb = kt * 64 + l4 * 8;
        bf16x8 bfr[2][4], afr[2][4];
#pragma unroll
        for (int ks = 0; ks < 2; ++ks)
#pragma unroll
            for (int j = 0; j < 4; ++j)
                bfr[ks][j] = *(const bf16x8*)(wT + (size_t)(n0 + j * 16 + l15) * K + kb + ks * 32);
#pragma unroll
        for (int ks = 0; ks < 2; ++ks)
#pragma unroll
            for (int i = 0; i < 4; ++i)
                afr[ks][i] = load_a_frag<RELU_A>(A + (size_t)rowm[i] * K + kb + ks * 32);
#pragma unroll
        for (int ks = 0; ks < 2; ++ks)
#pragma unroll
            for (int i = 0; i < 4; ++i)
#pragma unroll
                for (int j = 0; j < 4; ++j)
                    acc[i][j] = __builtin_amdgcn_mfma_f32_16x16x32_bf16(bfr[ks][j], afr[ks][i], acc[i][j], 0, 0, 0);
    }

#pragma unroll
    for (int i = 0; i < 4; ++i) {
        const int m = m0 + i * 16 + l15;
        if (m < M) {
#pragma unroll
            for (int j = 0; j < 4; ++j) {
                const size_t oi = (size_t)m * N + n0 + j * 16 + l4 * 4;
                float4 v = { acc[i][j][0], acc[i][j][1], acc[i][j][2], acc[i][j][3] };
                if (MODE == 2) {
                    const float4 ea = *(const float4*)(epi_a + oi);
                    const float4 ex = *(const float4*)(epi_x + oi);
                    v.x = fmaxf(v.x + ea.x, 0.f) + ex.x;
                    v.y = fmaxf(v.y + ea.y, 0.f) + ex.y;
                    v.z = fmaxf(v.z + ea.z, 0.f) + ex.z;
                    v.w = fmaxf(v.w + ea.w, 0.f) + ex.w;
                }
                *(float4*)(out + oi) = v;
            }
        }
    }
}

// ---------------------------------------------------------------------------
// e-GEMM: e[320000][256] bf16 = edge_attr[320000][64] @ W_e, rows scattered to
// CSR slots via perm. Block = 4 waves (one 64-col tile each); B hoisted into
// registers (K=64); A fragments straight from global; LDS only for the output
// transpose so stores are 128B-contiguous per thread.
__global__ __launch_bounds__(256) void egemm_kernel(const float* __restrict__ A,
                                                    const unsigned short* __restrict__ wT,
                                                    unsigned short* __restrict__ e_out,
                                                    const int* __restrict__ perm)
{
    __shared__ unsigned short et[64 * 264];   // 33792 B
    const int tid  = threadIdx.x;
    const int wave = tid >> 6;
    const int lane = tid & 63;
    const int l15  = lane & 15;
    const int l4   = lane >> 4;
    const int wc0  = wave * 64;

    // Hoist B fragments: 8 x bf16x8 = 32 VGPRs, same for all tiles.
    bf16x8 bfr[2][4];
#pragma unroll
    for (int ks = 0; ks < 2; ++ks)
#pragma unroll
        for (int j = 0; j < 4; ++j)
            bfr[ks][j] = *(const bf16x8*)(wT + (size_t)(wc0 + j * 16 + l15) * 64 + ks * 32 + l4 * 8);

    const int lrow = tid >> 2;      // 0..63  (store phase)
    const int lcol = tid & 3;       // 128B chunk

    for (int mt = blockIdx.x; mt < N_EDGES / 64; mt += gridDim.x) {
        const int m0 = mt * 64;
        f32x4 acc[4][4];
#pragma unroll
        for (int i = 0; i < 4; ++i)
#pragma unroll
            for (int j = 0; j < 4; ++j) acc[i][j] = f32x4{0.f, 0.f, 0.f, 0.f};

        bf16x8 afr[2][4];
#pragma unroll
        for (int ks = 0; ks < 2; ++ks)
#pragma unroll
            for (int i = 0; i < 4; ++i)
                afr[ks][i] = load_a_frag<false>(A + (size_t)(m0 + i * 16 + l15) * 64 + ks * 32 + l4 * 8);
#pragma unroll
        for (int ks = 0; ks < 2; ++ks)
#pragma unroll
            for (int i = 0; i < 4; ++i)
#pragma unroll
                for (int j = 0; j < 4; ++j)
                    acc[i][j] = __builtin_amdgcn_mfma_f32_16x16x32_bf16(afr[ks][i], bfr[ks][j], acc[i][j], 0, 0, 0);

        __syncthreads();   // previous iteration's et reads complete
#pragma unroll
        for (int i = 0; i < 4; ++i) {
            const int rb = i * 16 + l4 * 4;
#pragma unroll
            for (int j = 0; j < 4; ++j) {
                const int col = wc0 + j * 16 + l15;
#pragma unroll
                for (int r = 0; r < 4; ++r)
                    et[(rb + r) * 264 + col] = f2b(acc[i][j][r]);
            }
        }
        __syncthreads();
        const int orow = perm[m0 + lrow];
        unsigned short* outp = e_out + (size_t)orow * 256 + lcol * 64;
        const unsigned short* ep = et + lrow * 264 + lcol * 64;
#pragma unroll
        for (int v = 0; v < 8; ++v)
            *(uint4*)(outp + v * 8) = *(const uint4*)(ep + v * 8);
    }
}

// ---------------------------------------------------------------------------
// One propagation hop. Wave-per-node, 4 dims/lane. e pre-permuted to CSR
// order (sequential stream).
__global__ __launch_bounds__(256) void hop_kernel(const float* __restrict__ h_prev1,
                                                  const float* __restrict__ h_prev2,
                                                  const unsigned short* __restrict__ e,
                                                  const int* __restrict__ row_start,
                                                  const int* __restrict__ csr_src,
                                                  float* __restrict__ h_out)
{
    const int wave = threadIdx.x >> 6;
    const int lane = threadIdx.x & 63;
    const int n = blockIdx.x * 4 + wave;
    const int d4 = lane * 4;
    const int rb = row_start[n];
    const int re = row_start[n + 1];

    float4 acc = {0.f, 0.f, 0.f, 0.f};
    int s = rb;
    for (; s + 4 <= re; s += 4) {
        const int i0 = csr_src[s];
        const int i1 = csr_src[s + 1];
        const int i2 = csr_src[s + 2];
        const int i3 = csr_src[s + 3];
        const ushort4 e0 = *(const ushort4*)(e + (size_t)(s + 0) * DIM + d4);
        const ushort4 e1 = *(const ushort4*)(e + (size_t)(s + 1) * DIM + d4);
        const ushort4 e2 = *(const ushort4*)(e + (size_t)(s + 2) * DIM + d4);
        const ushort4 e3 = *(const ushort4*)(e + (size_t)(s + 3) * DIM + d4);
        const float4 h0 = *(const float4*)(h_prev1 + (size_t)i0 * DIM + d4);
        const float4 h1 = *(const float4*)(h_prev1 + (size_t)i1 * DIM + d4);
        const float4 h2 = *(const float4*)(h_prev1 + (size_t)i2 * DIM + d4);
        const float4 h3 = *(const float4*)(h_prev1 + (size_t)i3 * DIM + d4);
        acc.x += fmaxf(h0.x + b2f(e0.x), 0.f) + fmaxf(h1.x + b2f(e1.x), 0.f) +
                 fmaxf(h2.x + b2f(e2.x), 0.f) + fmaxf(h3.x + b2f(e3.x), 0.f);
        acc.y += fmaxf(h0.y + b2f(e0.y), 0.f) + fmaxf(h1.y + b2f(e1.y), 0.f) +
                 fmaxf(h2.y + b2f(e2.y), 0.f) + fmaxf(h3.y + b2f(e3.y), 0.f);
        acc.z += fmaxf(h0.z + b2f(e0.z), 0.f) + fmaxf(h1.z + b2f(e1.z), 0.f) +
                 fmaxf(h2.z + b2f(e2.z), 0.f) + fmaxf(h3.z + b2f(e3.z), 0.f);
        acc.w += fmaxf(h0.w + b2f(e0.w), 0.f) + fmaxf(h1.w + b2f(e1.w), 0.f) +
                 fmaxf(h2.w + b2f(e2.w), 0.f) + fmaxf(h3.w + b2f(e3.w), 0.f);
    }
    for (; s < re; ++s) {
        const int sr = csr_src[s];
        const ushort4 ev = *(const ushort4*)(e + (size_t)s * DIM + d4);
        const float4 hv = *(const float4*)(h_prev1 + (size_t)sr * DIM + d4);
        acc.x += fmaxf(hv.x + b2f(ev.x), 0.f);
        acc.y += fmaxf(hv.y + b2f(ev.y), 0.f);
        acc.z += fmaxf(hv.z + b2f(ev.z), 0.f);
        acc.w += fmaxf(hv.w + b2f(ev.w), 0.f);
    }
    float4 r = acc;
    if (h_prev2) {
        const float gd = GAMMA * (float)(re - rb);
        const float4 p2 = *(const float4*)(h_prev2 + (size_t)n * DIM + d4);
        r.x -= gd * p2.x; r.y -= gd * p2.y; r.z -= gd * p2.z; r.w -= gd * p2.w;
    }
    *(float4*)(h_out + (size_t)n * DIM + d4) = r;
}

// ---------------------------------------------------------------------------
// Hop attention: wave w == head w (64 lanes == 64 head dims).
__global__ __launch_bounds__(256) void attn_kernel(const float* __restrict__ h0,
                                                   const float* __restrict__ h1,
                                                   const float* __restrict__ h2,
                                                   const float* __restrict__ h3,
                                                   const float* __restrict__ att_a,
                                                   float* __restrict__ out)
{
    const int n = blockIdx.x;
    const int t = threadIdx.x;
    const size_t i = (size_t)n * DIM + t;
    const float q = h0[i];
    float hk[4];
    hk[0] = q; hk[1] = h1[i]; hk[2] = h2[i]; hk[3] = h3[i];
    const float a = att_a[t];
    float sc[4];
#pragma unroll
    for (int k = 0; k < 4; ++k) {
        float v = tanhf(hk[k] + q) * a;
#pragma unroll
        for (int off = 32; off > 0; off >>= 1)
            v += __shfl_xor(v, off, 64);
        sc[k] = v;
    }
    const float mx = fmaxf(fmaxf(sc[0], sc[1]), fmaxf(sc[2], sc[3]));
    float ex[4], se = 0.f;
#pragma unroll
    for (int k = 0; k < 4; ++k) { ex[k] = __expf(sc[k] - mx); se += ex[k]; }
    const float inv = 1.f / se;
    float o = 0.f;
#pragma unroll
    for (int k = 0; k < 4; ++k) o += ex[k] * inv * hk[k];
    out[i] = o;
}

// ---------------------------------------------------------------------------
extern "C" void kernel_launch(void* const* d_in, const int* in_sizes, int n_in,
                              void* d_out, int out_size, void* d_ws, size_t ws_size,
                              hipStream_t stream)
{
    const float*    x         = (const float*)d_in[0];
    const unsigned* ei        = (const unsigned*)d_in[1];
    const float*    edge_attr = (const float*)d_in[2];
    const float*    W_x       = (const float*)d_in[3];
    const float*    W_e       = (const float*)d_in[4];
    const float*    att_a     = (const float*)d_in[5];
    const float*    W_ff1     = (const float*)d_in[6];
    const float*    W_ff2     = (const float*)d_in[7];

    char* ws = (char*)d_ws;
    size_t off = 0;
    auto alloc = [&](size_t bytes) -> void* {
        void* p = ws + off;
        off = (off + bytes + 255) & ~(size_t)255;
        return p;
    };
    int*   flag      = (int*)alloc(4);
    int*   src32     = (int*)alloc((size_t)N_EDGES * 4);
    int*   dst32     = (int*)alloc((size_t)N_EDGES * 4);
    int*   counts    = (int*)alloc((size_t)2 * N_NODES * 4);
    int*   fillc     = counts + N_NODES;
    int*   row_start = (int*)alloc((size_t)(N_NODES + 1) * 4);
    int*   perm      = (int*)alloc((size_t)N_EDGES * 4);
    int*   csr_src   = (int*)alloc((size_t)N_EDGES * 4);
    float* h0        = (float*)alloc((size_t)N_NODES * DIM * 4);
    float* h1        = (float*)alloc((size_t)N_NODES * DIM * 4);
    float* h2        = (float*)alloc((size_t)N_NODES * DIM * 4);
    float* h3        = (float*)alloc((size_t)N_NODES * DIM * 4);
    unsigned short* e_bf = (unsigned short*)alloc((size_t)N_EDGES * DIM * 2);
    float* attn_out  = (float*)alloc((size_t)N_NODES * DIM * 4);
    float* hidden    = (float*)alloc((size_t)N_NODES * FF_HIDDEN * 4);
    unsigned short* wxT   = (unsigned short*)alloc((size_t)DIM * DIM * 2);
    unsigned short* weT   = (unsigned short*)alloc((size_t)DIM * EDGE_DIM * 2);
    unsigned short* wff1T = (unsigned short*)alloc((size_t)FF_HIDDEN * DIM * 2);
    unsigned short* wff2T = (unsigned short*)alloc((size_t)DIM * FF_HIDDEN * 2);
    if (off > ws_size) return;

    const int egrid = (N_EDGES + 255) / 256;

    hipMemsetAsync(counts, 0, (size_t)2 * N_NODES * 4, stream);
    detect_kernel<<<1, 256, 0, stream>>>(ei, flag);
    convert_kernel<<<egrid, 256, 0, stream>>>(ei, flag, src32, dst32, counts);
    scan_kernel<<<1, 256, 0, stream>>>(counts, row_start);
    fill_kernel<<<egrid, 256, 0, stream>>>(src32, dst32, row_start, fillc, perm, csr_src);

    wconv_kernel<<<(DIM * DIM + 255) / 256, 256, 0, stream>>>(W_x, wxT, DIM, DIM);
    wconv_kernel<<<(EDGE_DIM * DIM + 255) / 256, 256, 0, stream>>>(W_e, weT, EDGE_DIM, DIM);
    wconv_kernel<<<(DIM * FF_HIDDEN + 255) / 256, 256, 0, stream>>>(W_ff1, wff1T, DIM, FF_HIDDEN);
    wconv_kernel<<<(FF_HIDDEN * DIM + 255) / 256, 256, 0, stream>>>(W_ff2, wff2T, FF_HIDDEN, DIM);

    // h0 = x @ W_x   (M=10000, K=256, N=256)
    wgemm_f32<0, false><<<dim3(157, 4), 64, 0, stream>>>(x, wxT, h0,
        N_NODES, DIM, DIM, nullptr, nullptr);
    // e = edge_attr @ W_e -> bf16, rows scattered to CSR slots
    egemm_kernel<<<1250, 256, 0, stream>>>(edge_attr, weT, e_bf, perm);

    hop_kernel<<<N_NODES / 4, 256, 0, stream>>>(h0, nullptr, e_bf, row_start, csr_src, h1);
    hop_kernel<<<N_NODES / 4, 256, 0, stream>>>(h1, h0,      e_bf, row_start, csr_src, h2);
    hop_kernel<<<N_NODES / 4, 256, 0, stream>>>(h2, h1,      e_bf, row_start, csr_src, h3);

    attn_kernel<<<N_NODES, 256, 0, stream>>>(h0, h1, h2, h3, att_a, attn_out);

    // hidden = attn_out @ W_ff1   (M=10000, K=256, N=512)
    wgemm_f32<0, false><<<dim3(157, 8), 64, 0, stream>>>(attn_out, wff1T, hidden,
        N_NODES, DIM, FF_HIDDEN, nullptr, nullptr);
    // d_out = x + relu(attn_out + relu(hidden) @ W_ff2)   (M=10000, K=512, N=256)
    wgemm_f32<2, true><<<dim3(157, 4), 64, 0, stream>>>(hidden, wff2T, (float*)d_out,
        N_NODES, FF_HIDDEN, DIM, attn_out, x);
}

// Round 7
// 395.725 us; speedup vs baseline: 1.1520x; 1.1520x over previous
//
#include <hip/hip_runtime.h>
#include <hip/hip_bf16.h>

#define N_NODES   10000
#define N_EDGES   320000
#define DIM       256
#define EDGE_DIM  64
#define FF_HIDDEN 512
#define GAMMA     0.5f

typedef __attribute__((ext_vector_type(8))) short bf16x8;
typedef __attribute__((ext_vector_type(4))) float f32x4;

static __device__ __forceinline__ unsigned short f2b(float f)
{
    union { __hip_bfloat16 b; unsigned short u; } c;
    c.b = __float2bfloat16(f);
    return c.u;
}
static __device__ __forceinline__ float b2f(unsigned short u)
{
    union { unsigned u32; float f; } c;
    c.u32 = ((unsigned)u) << 16;
    return c.f;
}

// Build one bf16x8 A-fragment from 8 consecutive f32 (32B).
static __device__ __forceinline__ bf16x8 load_a_frag(const float* __restrict__ p)
{
    const float4 f0 = *(const float4*)p;
    const float4 f1 = *(const float4*)(p + 4);
    bf16x8 r;
    r[0] = (short)f2b(f0.x); r[1] = (short)f2b(f0.y);
    r[2] = (short)f2b(f0.z); r[3] = (short)f2b(f0.w);
    r[4] = (short)f2b(f1.x); r[5] = (short)f2b(f1.y);
    r[6] = (short)f2b(f1.z); r[7] = (short)f2b(f1.w);
    return r;
}

// ---------------------------------------------------------------------------
// Edge-index dtype probe.
__global__ __launch_bounds__(256) void detect_kernel(const unsigned* __restrict__ ei,
                                                     int* __restrict__ flag)
{
    __shared__ int bad;
    if (threadIdx.x == 0) bad = 0;
    __syncthreads();
    int b = 0;
    for (int i = threadIdx.x; i < 1024; i += 256)
        if (ei[2 * i + 1] != 0u) b = 1;
    if (b) atomicAdd(&bad, 1);
    __syncthreads();
    if (threadIdx.x == 0) *flag = (bad == 0) ? 1 : 0;
}

__global__ __launch_bounds__(256) void convert_kernel(const unsigned* __restrict__ ei,
                                                      const int* __restrict__ flag,
                                                      int* __restrict__ src, int* __restrict__ dst,
                                                      int* __restrict__ counts)
{
    const int i = blockIdx.x * 256 + threadIdx.x;
    if (i >= N_EDGES) return;
    const int f = *flag;
    int s, d;
    if (f) { s = (int)ei[2 * i]; d = (int)ei[2 * (N_EDGES + i)]; }
    else   { s = (int)ei[i];     d = (int)ei[N_EDGES + i]; }
    src[i] = s;
    dst[i] = d;
    atomicAdd(&counts[d], 1);
}

__global__ __launch_bounds__(256) void scan_kernel(const int* __restrict__ counts,
                                                   int* __restrict__ row_start)
{
    __shared__ int lds[256];
    const int t = threadIdx.x;
    int vals[40];
    int tot = 0;
    const int base = t * 40;
#pragma unroll
    for (int j = 0; j < 40; ++j) {
        const int idx = base + j;
        const int c = (idx < N_NODES) ? counts[idx] : 0;
        vals[j] = tot;
        tot += c;
    }
    lds[t] = tot;
    __syncthreads();
    for (int off = 1; off < 256; off <<= 1) {
        const int tmp = (t >= off) ? lds[t - off] : 0;
        __syncthreads();
        lds[t] += tmp;
        __syncthreads();
    }
    const int ebase = lds[t] - tot;
#pragma unroll
    for (int j = 0; j < 40; ++j) {
        const int idx = base + j;
        if (idx < N_NODES) row_start[idx] = ebase + vals[j];
    }
    if (t == 0) row_start[N_NODES] = N_EDGES;
}

// Records perm[edge] = CSR slot so e can be written pre-permuted.
__global__ __launch_bounds__(256) void fill_kernel(const int* __restrict__ src,
                                                   const int* __restrict__ dst,
                                                   const int* __restrict__ row_start,
                                                   int* __restrict__ fillc,
                                                   int* __restrict__ perm,
                                                   int* __restrict__ csr_src)
{
    const int i = blockIdx.x * 256 + threadIdx.x;
    if (i >= N_EDGES) return;
    const int d = dst[i];
    const int pos = atomicAdd(&fillc[d], 1);
    const int slot = row_start[d] + pos;
    perm[i] = slot;
    csr_src[slot] = src[i];
}

// ---------------------------------------------------------------------------
// W[k][n] f32 -> wT[n][k] bf16
__global__ __launch_bounds__(256) void wconv_kernel(const float* __restrict__ W,
                                                    unsigned short* __restrict__ wT,
                                                    int K, int N)
{
    const int i = blockIdx.x * 256 + threadIdx.x;
    if (i >= K * N) return;
    const int k = i / N, n = i - k * N;
    wT[(size_t)n * K + k] = f2b(W[i]);
}

// ---------------------------------------------------------------------------
// Wave-level register GEMM (no LDS). Block = 4 waves; wave owns a 64x64 tile
// (64 rows x 64 of the 256 block cols). Swapped-operand MFMA: lane holds
// (row = l15, 4 consecutive cols = l4*4+reg) => direct 8B/16B stores.
// ABF16: A is bf16 (else f32, converted on load).
// MODE 0: bf16 out. MODE 1: bf16 out with relu. MODE 2: f32 out,
//   out = epi_x + relu(b2f(epi_a) + acc)   (ff2 fused epilogue).
template <bool ABF16, int MODE>
__global__ __launch_bounds__(256) void wgemm(const void* __restrict__ Av,
                                             const unsigned short* __restrict__ wT,
                                             void* __restrict__ outv,
                                             int M, int K, int N,
                                             const unsigned short* __restrict__ epi_a,
                                             const float* __restrict__ epi_x)
{
    const int tid  = threadIdx.x;
    const int wave = tid >> 6;
    const int lane = tid & 63;
    const int l15  = lane & 15;
    const int l4   = lane >> 4;
    const int m0   = blockIdx.x * 64;
    const int n0   = blockIdx.y * 256 + wave * 64;

    f32x4 acc[4][4];
#pragma unroll
    for (int i = 0; i < 4; ++i)
#pragma unroll
        for (int j = 0; j < 4; ++j) acc[i][j] = f32x4{0.f, 0.f, 0.f, 0.f};

    int rowm[4];
#pragma unroll
    for (int i = 0; i < 4; ++i) rowm[i] = min(m0 + i * 16 + l15, M - 1);

    const int nk = K >> 6;
    for (int kt = 0; kt < nk; ++kt) {
        const int kb = kt * 64 + l4 * 8;
        bf16x8 bfr[2][4], afr[2][4];
#pragma unroll
        for (int ks = 0; ks < 2; ++ks)
#pragma unroll
            for (int j = 0; j < 4; ++j)
                bfr[ks][j] = *(const bf16x8*)(wT + (size_t)(n0 + j * 16 + l15) * K + kb + ks * 32);
#pragma unroll
        for (int ks = 0; ks < 2; ++ks)
#pragma unroll
            for (int i = 0; i < 4; ++i) {
                if (ABF16)
                    afr[ks][i] = *(const bf16x8*)((const unsigned short*)Av + (size_t)rowm[i] * K + kb + ks * 32);
                else
                    afr[ks][i] = load_a_frag((const float*)Av + (size_t)rowm[i] * K + kb + ks * 32);
            }
#pragma unroll
        for (int ks = 0; ks < 2; ++ks)
#pragma unroll
            for (int i = 0; i < 4; ++i)
#pragma unroll
                for (int j = 0; j < 4; ++j)
                    acc[i][j] = __builtin_amdgcn_mfma_f32_16x16x32_bf16(bfr[ks][j], afr[ks][i], acc[i][j], 0, 0, 0);
    }

#pragma unroll
    for (int i = 0; i < 4; ++i) {
        const int m = m0 + i * 16 + l15;
        if (m < M) {
#pragma unroll
            for (int j = 0; j < 4; ++j) {
                const size_t oi = (size_t)m * N + n0 + j * 16 + l4 * 4;
                if (MODE == 2) {
                    const ushort4 ea = *(const ushort4*)(epi_a + oi);
                    const float4  ex = *(const float4*)(epi_x + oi);
                    float4 v;
                    v.x = fmaxf(acc[i][j][0] + b2f(ea.x), 0.f) + ex.x;
                    v.y = fmaxf(acc[i][j][1] + b2f(ea.y), 0.f) + ex.y;
                    v.z = fmaxf(acc[i][j][2] + b2f(ea.z), 0.f) + ex.z;
                    v.w = fmaxf(acc[i][j][3] + b2f(ea.w), 0.f) + ex.w;
                    *(float4*)((float*)outv + oi) = v;
                } else {
                    float a0 = acc[i][j][0], a1 = acc[i][j][1];
                    float a2 = acc[i][j][2], a3 = acc[i][j][3];
                    if (MODE == 1) {
                        a0 = fmaxf(a0, 0.f); a1 = fmaxf(a1, 0.f);
                        a2 = fmaxf(a2, 0.f); a3 = fmaxf(a3, 0.f);
                    }
                    ushort4 u;
                    u.x = f2b(a0); u.y = f2b(a1); u.z = f2b(a2); u.w = f2b(a3);
                    *(ushort4*)((unsigned short*)outv + oi) = u;
                }
            }
        }
    }
}

// ---------------------------------------------------------------------------
// e-GEMM: e[320000][256] bf16 = edge_attr[320000][64] @ W_e, rows scattered
// to CSR slots via perm. No LDS, no barriers: B register-hoisted, swapped
// MFMA => lane holds 4 consecutive dims of one edge row => ushort4 stores.
__global__ __launch_bounds__(256) void egemm_kernel(const float* __restrict__ A,
                                                    const unsigned short* __restrict__ wT,
                                                    unsigned short* __restrict__ e_out,
                                                    const int* __restrict__ perm)
{
    const int tid  = threadIdx.x;
    const int wave = tid >> 6;
    const int lane = tid & 63;
    const int l15  = lane & 15;
    const int l4   = lane >> 4;
    const int wc0  = wave * 64;
    const int m0   = blockIdx.x * 64;

    bf16x8 bfr[2][4];
#pragma unroll
    for (int ks = 0; ks < 2; ++ks)
#pragma unroll
        for (int j = 0; j < 4; ++j)
            bfr[ks][j] = *(const bf16x8*)(wT + (size_t)(wc0 + j * 16 + l15) * 64 + ks * 32 + l4 * 8);

    int prow[4];
#pragma unroll
    for (int i = 0; i < 4; ++i) prow[i] = perm[m0 + i * 16 + l15];

    bf16x8 afr[2][4];
#pragma unroll
    for (int ks = 0; ks < 2; ++ks)
#pragma unroll
        for (int i = 0; i < 4; ++i)
            afr[ks][i] = load_a_frag(A + (size_t)(m0 + i * 16 + l15) * 64 + ks * 32 + l4 * 8);

    f32x4 acc[4][4];
#pragma unroll
    for (int i = 0; i < 4; ++i)
#pragma unroll
        for (int j = 0; j < 4; ++j) acc[i][j] = f32x4{0.f, 0.f, 0.f, 0.f};
#pragma unroll
    for (int ks = 0; ks < 2; ++ks)
#pragma unroll
        for (int i = 0; i < 4; ++i)
#pragma unroll
            for (int j = 0; j < 4; ++j)
                acc[i][j] = __builtin_amdgcn_mfma_f32_16x16x32_bf16(bfr[ks][j], afr[ks][i], acc[i][j], 0, 0, 0);

#pragma unroll
    for (int i = 0; i < 4; ++i) {
#pragma unroll
        for (int j = 0; j < 4; ++j) {
            ushort4 u;
            u.x = f2b(acc[i][j][0]); u.y = f2b(acc[i][j][1]);
            u.z = f2b(acc[i][j][2]); u.w = f2b(acc[i][j][3]);
            *(ushort4*)(e_out + (size_t)prow[i] * 256 + wc0 + j * 16 + l4 * 4) = u;
        }
    }
}

// ---------------------------------------------------------------------------
// One propagation hop, all-bf16 h. Wave-per-node, 4 dims/lane, 8-edge MLP.
// e pre-permuted to CSR order (pure sequential stream).
__global__ __launch_bounds__(256) void hop_kernel(const unsigned short* __restrict__ h_prev1,
                                                  const unsigned short* __restrict__ h_prev2,
                                                  const unsigned short* __restrict__ e,
                                                  const int* __restrict__ row_start,
                                                  const int* __restrict__ csr_src,
                                                  unsigned short* __restrict__ h_out)
{
    const int wave = threadIdx.x >> 6;
    const int lane = threadIdx.x & 63;
    const int n = blockIdx.x * 4 + wave;
    const int d4 = lane * 4;
    const int rb = row_start[n];
    const int re = row_start[n + 1];

    float4 acc = {0.f, 0.f, 0.f, 0.f};
    int s = rb;
    for (; s + 8 <= re; s += 8) {
        int idx[8];
        ushort4 ev[8], hv[8];
#pragma unroll
        for (int u = 0; u < 8; ++u) idx[u] = csr_src[s + u];
#pragma unroll
        for (int u = 0; u < 8; ++u) ev[u] = *(const ushort4*)(e + (size_t)(s + u) * DIM + d4);
#pragma unroll
        for (int u = 0; u < 8; ++u) hv[u] = *(const ushort4*)(h_prev1 + (size_t)idx[u] * DIM + d4);
#pragma unroll
        for (int u = 0; u < 8; ++u) {
            acc.x += fmaxf(b2f(hv[u].x) + b2f(ev[u].x), 0.f);
            acc.y += fmaxf(b2f(hv[u].y) + b2f(ev[u].y), 0.f);
            acc.z += fmaxf(b2f(hv[u].z) + b2f(ev[u].z), 0.f);
            acc.w += fmaxf(b2f(hv[u].w) + b2f(ev[u].w), 0.f);
        }
    }
    for (; s < re; ++s) {
        const int sr = csr_src[s];
        const ushort4 ev = *(const ushort4*)(e + (size_t)s * DIM + d4);
        const ushort4 hv = *(const ushort4*)(h_prev1 + (size_t)sr * DIM + d4);
        acc.x += fmaxf(b2f(hv.x) + b2f(ev.x), 0.f);
        acc.y += fmaxf(b2f(hv.y) + b2f(ev.y), 0.f);
        acc.z += fmaxf(b2f(hv.z) + b2f(ev.z), 0.f);
        acc.w += fmaxf(b2f(hv.w) + b2f(ev.w), 0.f);
    }
    if (h_prev2) {
        const float gd = GAMMA * (float)(re - rb);
        const ushort4 p2 = *(const ushort4*)(h_prev2 + (size_t)n * DIM + d4);
        acc.x -= gd * b2f(p2.x); acc.y -= gd * b2f(p2.y);
        acc.z -= gd * b2f(p2.z); acc.w -= gd * b2f(p2.w);
    }
    ushort4 o;
    o.x = f2b(acc.x); o.y = f2b(acc.y); o.z = f2b(acc.z); o.w = f2b(acc.w);
    *(ushort4*)(h_out + (size_t)n * DIM + d4) = o;
}

// ---------------------------------------------------------------------------
// Hop attention: wave w == head w (64 lanes == 64 head dims). bf16 in/out.
__global__ __launch_bounds__(256) void attn_kernel(const unsigned short* __restrict__ h0,
                                                   const unsigned short* __restrict__ h1,
                                                   const unsigned short* __restrict__ h2,
                                                   const unsigned short* __restrict__ h3,
                                                   const float* __restrict__ att_a,
                                                   unsigned short* __restrict__ out)
{
    const int n = blockIdx.x;
    const int t = threadIdx.x;
    const size_t i = (size_t)n * DIM + t;
    const float q = b2f(h0[i]);
    float hk[4];
    hk[0] = q; hk[1] = b2f(h1[i]); hk[2] = b2f(h2[i]); hk[3] = b2f(h3[i]);
    const float a = att_a[t];
    float sc[4];
#pragma unroll
    for (int k = 0; k < 4; ++k) {
        float v = tanhf(hk[k] + q) * a;
#pragma unroll
        for (int off = 32; off > 0; off >>= 1)
            v += __shfl_xor(v, off, 64);
        sc[k] = v;
    }
    const float mx = fmaxf(fmaxf(sc[0], sc[1]), fmaxf(sc[2], sc[3]));
    float ex[4], se = 0.f;
#pragma unroll
    for (int k = 0; k < 4; ++k) { ex[k] = __expf(sc[k] - mx); se += ex[k]; }
    const float inv = 1.f / se;
    float o = 0.f;
#pragma unroll
    for (int k = 0; k < 4; ++k) o += ex[k] * inv * hk[k];
    out[i] = f2b(o);
}

// ---------------------------------------------------------------------------
extern "C" void kernel_launch(void* const* d_in, const int* in_sizes, int n_in,
                              void* d_out, int out_size, void* d_ws, size_t ws_size,
                              hipStream_t stream)
{
    const float*    x         = (const float*)d_in[0];
    const unsigned* ei        = (const unsigned*)d_in[1];
    const float*    edge_attr = (const float*)d_in[2];
    const float*    W_x       = (const float*)d_in[3];
    const float*    W_e       = (const float*)d_in[4];
    const float*    att_a     = (const float*)d_in[5];
    const float*    W_ff1     = (const float*)d_in[6];
    const float*    W_ff2     = (const float*)d_in[7];

    char* ws = (char*)d_ws;
    size_t off = 0;
    auto alloc = [&](size_t bytes) -> void* {
        void* p = ws + off;
        off = (off + bytes + 255) & ~(size_t)255;
        return p;
    };
    int*   flag      = (int*)alloc(4);
    int*   src32     = (int*)alloc((size_t)N_EDGES * 4);
    int*   dst32     = (int*)alloc((size_t)N_EDGES * 4);
    int*   counts    = (int*)alloc((size_t)2 * N_NODES * 4);
    int*   fillc     = counts + N_NODES;
    int*   row_start = (int*)alloc((size_t)(N_NODES + 1) * 4);
    int*   perm      = (int*)alloc((size_t)N_EDGES * 4);
    int*   csr_src   = (int*)alloc((size_t)N_EDGES * 4);
    unsigned short* h0b   = (unsigned short*)alloc((size_t)N_NODES * DIM * 2);
    unsigned short* h1b   = (unsigned short*)alloc((size_t)N_NODES * DIM * 2);
    unsigned short* h2b   = (unsigned short*)alloc((size_t)N_NODES * DIM * 2);
    unsigned short* h3b   = (unsigned short*)alloc((size_t)N_NODES * DIM * 2);
    unsigned short* e_bf  = (unsigned short*)alloc((size_t)N_EDGES * DIM * 2);
    unsigned short* attnb = (unsigned short*)alloc((size_t)N_NODES * DIM * 2);
    unsigned short* hidb  = (unsigned short*)alloc((size_t)N_NODES * FF_HIDDEN * 2);
    unsigned short* wxT   = (unsigned short*)alloc((size_t)DIM * DIM * 2);
    unsigned short* weT   = (unsigned short*)alloc((size_t)DIM * EDGE_DIM * 2);
    unsigned short* wff1T = (unsigned short*)alloc((size_t)FF_HIDDEN * DIM * 2);
    unsigned short* wff2T = (unsigned short*)alloc((size_t)DIM * FF_HIDDEN * 2);
    if (off > ws_size) return;

    const int egrid = (N_EDGES + 255) / 256;

    hipMemsetAsync(counts, 0, (size_t)2 * N_NODES * 4, stream);
    detect_kernel<<<1, 256, 0, stream>>>(ei, flag);
    convert_kernel<<<egrid, 256, 0, stream>>>(ei, flag, src32, dst32, counts);
    scan_kernel<<<1, 256, 0, stream>>>(counts, row_start);
    fill_kernel<<<egrid, 256, 0, stream>>>(src32, dst32, row_start, fillc, perm, csr_src);

    wconv_kernel<<<(DIM * DIM + 255) / 256, 256, 0, stream>>>(W_x, wxT, DIM, DIM);
    wconv_kernel<<<(EDGE_DIM * DIM + 255) / 256, 256, 0, stream>>>(W_e, weT, EDGE_DIM, DIM);
    wconv_kernel<<<(DIM * FF_HIDDEN + 255) / 256, 256, 0, stream>>>(W_ff1, wff1T, DIM, FF_HIDDEN);
    wconv_kernel<<<(FF_HIDDEN * DIM + 255) / 256, 256, 0, stream>>>(W_ff2, wff2T, FF_HIDDEN, DIM);

    // h0 = x @ W_x -> bf16   (M=10000, K=256, N=256)
    wgemm<false, 0><<<dim3(157, 1), 256, 0, stream>>>(x, wxT, h0b,
        N_NODES, DIM, DIM, nullptr, nullptr);
    // e = edge_attr @ W_e -> bf16, rows scattered to CSR slots
    egemm_kernel<<<N_EDGES / 64, 256, 0, stream>>>(edge_attr, weT, e_bf, perm);

    hop_kernel<<<N_NODES / 4, 256, 0, stream>>>(h0b, nullptr, e_bf, row_start, csr_src, h1b);
    hop_kernel<<<N_NODES / 4, 256, 0, stream>>>(h1b, h0b,     e_bf, row_start, csr_src, h2b);
    hop_kernel<<<N_NODES / 4, 256, 0, stream>>>(h2b, h1b,     e_bf, row_start, csr_src, h3b);

    attn_kernel<<<N_NODES, 256, 0, stream>>>(h0b, h1b, h2b, h3b, att_a, attnb);

    // hidden = relu(attn @ W_ff1) -> bf16   (M=10000, K=256, N=512)
    wgemm<true, 1><<<dim3(157, 2), 256, 0, stream>>>(attnb, wff1T, hidb,
        N_NODES, DIM, FF_HIDDEN, nullptr, nullptr);
    // d_out = x + relu(attn + hidden @ W_ff2)   (M=10000, K=512, N=256)
    wgemm<true, 2><<<dim3(157, 1), 256, 0, stream>>>(hidb, wff2T, d_out,
        N_NODES, FF_HIDDEN, DIM, attnb, x);
}

// Round 8
// 395.138 us; speedup vs baseline: 1.1537x; 1.0015x over previous
//
#include <hip/hip_runtime.h>
#include <hip/hip_bf16.h>

#define N_NODES   10000
#define N_EDGES   320000
#define DIM       256
#define EDGE_DIM  64
#define FF_HIDDEN 512
#define GAMMA     0.5f

typedef __attribute__((ext_vector_type(8))) short bf16x8;
typedef __attribute__((ext_vector_type(4))) float f32x4;

static __device__ __forceinline__ unsigned short f2b(float f)
{
    union { __hip_bfloat16 b; unsigned short u; } c;
    c.b = __float2bfloat16(f);
    return c.u;
}
static __device__ __forceinline__ float b2f(unsigned short u)
{
    union { unsigned u32; float f; } c;
    c.u32 = ((unsigned)u) << 16;
    return c.f;
}

// Build one bf16x8 A-fragment from 8 consecutive f32 (32B).
static __device__ __forceinline__ bf16x8 load_a_frag(const float* __restrict__ p)
{
    const float4 f0 = *(const float4*)p;
    const float4 f1 = *(const float4*)(p + 4);
    bf16x8 r;
    r[0] = (short)f2b(f0.x); r[1] = (short)f2b(f0.y);
    r[2] = (short)f2b(f0.z); r[3] = (short)f2b(f0.w);
    r[4] = (short)f2b(f1.x); r[5] = (short)f2b(f1.y);
    r[6] = (short)f2b(f1.z); r[7] = (short)f2b(f1.w);
    return r;
}

// ---------------------------------------------------------------------------
// Edge-index dtype probe.
__global__ __launch_bounds__(256) void detect_kernel(const unsigned* __restrict__ ei,
                                                     int* __restrict__ flag)
{
    __shared__ int bad;
    if (threadIdx.x == 0) bad = 0;
    __syncthreads();
    int b = 0;
    for (int i = threadIdx.x; i < 1024; i += 256)
        if (ei[2 * i + 1] != 0u) b = 1;
    if (b) atomicAdd(&bad, 1);
    __syncthreads();
    if (threadIdx.x == 0) *flag = (bad == 0) ? 1 : 0;
}

__global__ __launch_bounds__(256) void convert_kernel(const unsigned* __restrict__ ei,
                                                      const int* __restrict__ flag,
                                                      int* __restrict__ src, int* __restrict__ dst,
                                                      int* __restrict__ counts)
{
    const int i = blockIdx.x * 256 + threadIdx.x;
    if (i >= N_EDGES) return;
    const int f = *flag;
    int s, d;
    if (f) { s = (int)ei[2 * i]; d = (int)ei[2 * (N_EDGES + i)]; }
    else   { s = (int)ei[i];     d = (int)ei[N_EDGES + i]; }
    src[i] = s;
    dst[i] = d;
    atomicAdd(&counts[d], 1);
}

__global__ __launch_bounds__(256) void scan_kernel(const int* __restrict__ counts,
                                                   int* __restrict__ row_start)
{
    __shared__ int lds[256];
    const int t = threadIdx.x;
    int vals[40];
    int tot = 0;
    const int base = t * 40;
#pragma unroll
    for (int j = 0; j < 40; ++j) {
        const int idx = base + j;
        const int c = (idx < N_NODES) ? counts[idx] : 0;
        vals[j] = tot;
        tot += c;
    }
    lds[t] = tot;
    __syncthreads();
    for (int off = 1; off < 256; off <<= 1) {
        const int tmp = (t >= off) ? lds[t - off] : 0;
        __syncthreads();
        lds[t] += tmp;
        __syncthreads();
    }
    const int ebase = lds[t] - tot;
#pragma unroll
    for (int j = 0; j < 40; ++j) {
        const int idx = base + j;
        if (idx < N_NODES) row_start[idx] = ebase + vals[j];
    }
    if (t == 0) row_start[N_NODES] = N_EDGES;
}

// csr_eid[slot] = edge id, csr_src[slot] = source node.
__global__ __launch_bounds__(256) void fill_kernel(const int* __restrict__ src,
                                                   const int* __restrict__ dst,
                                                   const int* __restrict__ row_start,
                                                   int* __restrict__ fillc,
                                                   int* __restrict__ csr_eid,
                                                   int* __restrict__ csr_src)
{
    const int i = blockIdx.x * 256 + threadIdx.x;
    if (i >= N_EDGES) return;
    const int d = dst[i];
    const int pos = atomicAdd(&fillc[d], 1);
    const int slot = row_start[d] + pos;
    csr_eid[slot] = i;
    csr_src[slot] = src[i];
}

// ---------------------------------------------------------------------------
// W[k][n] f32 -> wT[n][k] bf16
__global__ __launch_bounds__(256) void wconv_kernel(const float* __restrict__ W,
                                                    unsigned short* __restrict__ wT,
                                                    int K, int N)
{
    const int i = blockIdx.x * 256 + threadIdx.x;
    if (i >= K * N) return;
    const int k = i / N, n = i - k * N;
    wT[(size_t)n * K + k] = f2b(W[i]);
}

// ---------------------------------------------------------------------------
// Wave-level register GEMM (no LDS). Block = 4 waves; wave owns a 64x64 tile
// (64 rows x 64 of the 256 block cols). Swapped-operand MFMA: lane holds
// (row = l15, 4 consecutive cols = l4*4+reg) => direct 8B/16B stores.
// ABF16: A is bf16 (else f32, converted on load).
// MODE 0: bf16 out. MODE 1: bf16 out with relu. MODE 2: f32 out,
//   out = epi_x + relu(b2f(epi_a) + acc)   (ff2 fused epilogue).
template <bool ABF16, int MODE>
__global__ __launch_bounds__(256) void wgemm(const void* __restrict__ Av,
                                             const unsigned short* __restrict__ wT,
                                             void* __restrict__ outv,
                                             int M, int K, int N,
                                             const unsigned short* __restrict__ epi_a,
                                             const float* __restrict__ epi_x)
{
    const int tid  = threadIdx.x;
    const int wave = tid >> 6;
    const int lane = tid & 63;
    const int l15  = lane & 15;
    const int l4   = lane >> 4;
    const int m0   = blockIdx.x * 64;
    const int n0   = blockIdx.y * 256 + wave * 64;

    f32x4 acc[4][4];
#pragma unroll
    for (int i = 0; i < 4; ++i)
#pragma unroll
        for (int j = 0; j < 4; ++j) acc[i][j] = f32x4{0.f, 0.f, 0.f, 0.f};

    int rowm[4];
#pragma unroll
    for (int i = 0; i < 4; ++i) rowm[i] = min(m0 + i * 16 + l15, M - 1);

    const int nk = K >> 6;
    for (int kt = 0; kt < nk; ++kt) {
        const int kb = kt * 64 + l4 * 8;
        bf16x8 bfr[2][4], afr[2][4];
#pragma unroll
        for (int ks = 0; ks < 2; ++ks)
#pragma unroll
            for (int j = 0; j < 4; ++j)
                bfr[ks][j] = *(const bf16x8*)(wT + (size_t)(n0 + j * 16 + l15) * K + kb + ks * 32);
#pragma unroll
        for (int ks = 0; ks < 2; ++ks)
#pragma unroll
            for (int i = 0; i < 4; ++i) {
                if (ABF16)
                    afr[ks][i] = *(const bf16x8*)((const unsigned short*)Av + (size_t)rowm[i] * K + kb + ks * 32);
                else
                    afr[ks][i] = load_a_frag((const float*)Av + (size_t)rowm[i] * K + kb + ks * 32);
            }
#pragma unroll
        for (int ks = 0; ks < 2; ++ks)
#pragma unroll
            for (int i = 0; i < 4; ++i)
#pragma unroll
                for (int j = 0; j < 4; ++j)
                    acc[i][j] = __builtin_amdgcn_mfma_f32_16x16x32_bf16(bfr[ks][j], afr[ks][i], acc[i][j], 0, 0, 0);
    }

#pragma unroll
    for (int i = 0; i < 4; ++i) {
        const int m = m0 + i * 16 + l15;
        if (m < M) {
#pragma unroll
            for (int j = 0; j < 4; ++j) {
                const size_t oi = (size_t)m * N + n0 + j * 16 + l4 * 4;
                if (MODE == 2) {
                    const ushort4 ea = *(const ushort4*)(epi_a + oi);
                    const float4  ex = *(const float4*)(epi_x + oi);
                    float4 v;
                    v.x = fmaxf(acc[i][j][0] + b2f(ea.x), 0.f) + ex.x;
                    v.y = fmaxf(acc[i][j][1] + b2f(ea.y), 0.f) + ex.y;
                    v.z = fmaxf(acc[i][j][2] + b2f(ea.z), 0.f) + ex.z;
                    v.w = fmaxf(acc[i][j][3] + b2f(ea.w), 0.f) + ex.w;
                    *(float4*)((float*)outv + oi) = v;
                } else {
                    float a0 = acc[i][j][0], a1 = acc[i][j][1];
                    float a2 = acc[i][j][2], a3 = acc[i][j][3];
                    if (MODE == 1) {
                        a0 = fmaxf(a0, 0.f); a1 = fmaxf(a1, 0.f);
                        a2 = fmaxf(a2, 0.f); a3 = fmaxf(a3, 0.f);
                    }
                    ushort4 u;
                    u.x = f2b(a0); u.y = f2b(a1); u.z = f2b(a2); u.w = f2b(a3);
                    *(ushort4*)((unsigned short*)outv + oi) = u;
                }
            }
        }
    }
}

// ---------------------------------------------------------------------------
// e-GEMM, gather flavor: block owns CSR slots [m0, m0+64). A-rows are
// GATHERED from edge_attr via csr_eid (82 MB read side); e rows are stored
// SEQUENTIALLY (164 MB write side stays fully streamed). No LDS, no barriers.
__global__ __launch_bounds__(256) void egemm_kernel(const float* __restrict__ A,
                                                    const unsigned short* __restrict__ wT,
                                                    unsigned short* __restrict__ e_out,
                                                    const int* __restrict__ csr_eid)
{
    const int tid  = threadIdx.x;
    const int wave = tid >> 6;
    const int lane = tid & 63;
    const int l15  = lane & 15;
    const int l4   = lane >> 4;
    const int wc0  = wave * 64;
    const int m0   = blockIdx.x * 64;   // CSR slot base

    bf16x8 bfr[2][4];
#pragma unroll
    for (int ks = 0; ks < 2; ++ks)
#pragma unroll
        for (int j = 0; j < 4; ++j)
            bfr[ks][j] = *(const bf16x8*)(wT + (size_t)(wc0 + j * 16 + l15) * 64 + ks * 32 + l4 * 8);

    int eid[4];
#pragma unroll
    for (int i = 0; i < 4; ++i) eid[i] = csr_eid[m0 + i * 16 + l15];

    bf16x8 afr[2][4];
#pragma unroll
    for (int ks = 0; ks < 2; ++ks)
#pragma unroll
        for (int i = 0; i < 4; ++i)
            afr[ks][i] = load_a_frag(A + (size_t)eid[i] * 64 + ks * 32 + l4 * 8);

    f32x4 acc[4][4];
#pragma unroll
    for (int i = 0; i < 4; ++i)
#pragma unroll
        for (int j = 0; j < 4; ++j) acc[i][j] = f32x4{0.f, 0.f, 0.f, 0.f};
#pragma unroll
    for (int ks = 0; ks < 2; ++ks)
#pragma unroll
        for (int i = 0; i < 4; ++i)
#pragma unroll
            for (int j = 0; j < 4; ++j)
                acc[i][j] = __builtin_amdgcn_mfma_f32_16x16x32_bf16(bfr[ks][j], afr[ks][i], acc[i][j], 0, 0, 0);

#pragma unroll
    for (int i = 0; i < 4; ++i) {
#pragma unroll
        for (int j = 0; j < 4; ++j) {
            ushort4 u;
            u.x = f2b(acc[i][j][0]); u.y = f2b(acc[i][j][1]);
            u.z = f2b(acc[i][j][2]); u.w = f2b(acc[i][j][3]);
            *(ushort4*)(e_out + (size_t)(m0 + i * 16 + l15) * 256 + wc0 + j * 16 + l4 * 4) = u;
        }
    }
}

// ---------------------------------------------------------------------------
// One propagation hop, all-bf16 h. Wave-per-node, 4 dims/lane, 8-edge MLP.
// e pre-permuted to CSR order (pure sequential stream).
__global__ __launch_bounds__(256) void hop_kernel(const unsigned short* __restrict__ h_prev1,
                                                  const unsigned short* __restrict__ h_prev2,
                                                  const unsigned short* __restrict__ e,
                                                  const int* __restrict__ row_start,
                                                  const int* __restrict__ csr_src,
                                                  unsigned short* __restrict__ h_out)
{
    const int wave = threadIdx.x >> 6;
    const int lane = threadIdx.x & 63;
    const int n = blockIdx.x * 4 + wave;
    const int d4 = lane * 4;
    const int rb = row_start[n];
    const int re = row_start[n + 1];

    float4 acc = {0.f, 0.f, 0.f, 0.f};
    int s = rb;
    for (; s + 8 <= re; s += 8) {
        int idx[8];
        ushort4 ev[8], hv[8];
#pragma unroll
        for (int u = 0; u < 8; ++u) idx[u] = csr_src[s + u];
#pragma unroll
        for (int u = 0; u < 8; ++u) ev[u] = *(const ushort4*)(e + (size_t)(s + u) * DIM + d4);
#pragma unroll
        for (int u = 0; u < 8; ++u) hv[u] = *(const ushort4*)(h_prev1 + (size_t)idx[u] * DIM + d4);
#pragma unroll
        for (int u = 0; u < 8; ++u) {
            acc.x += fmaxf(b2f(hv[u].x) + b2f(ev[u].x), 0.f);
            acc.y += fmaxf(b2f(hv[u].y) + b2f(ev[u].y), 0.f);
            acc.z += fmaxf(b2f(hv[u].z) + b2f(ev[u].z), 0.f);
            acc.w += fmaxf(b2f(hv[u].w) + b2f(ev[u].w), 0.f);
        }
    }
    for (; s < re; ++s) {
        const int sr = csr_src[s];
        const ushort4 ev = *(const ushort4*)(e + (size_t)s * DIM + d4);
        const ushort4 hv = *(const ushort4*)(h_prev1 + (size_t)sr * DIM + d4);
        acc.x += fmaxf(b2f(hv.x) + b2f(ev.x), 0.f);
        acc.y += fmaxf(b2f(hv.y) + b2f(ev.y), 0.f);
        acc.z += fmaxf(b2f(hv.z) + b2f(ev.z), 0.f);
        acc.w += fmaxf(b2f(hv.w) + b2f(ev.w), 0.f);
    }
    if (h_prev2) {
        const float gd = GAMMA * (float)(re - rb);
        const ushort4 p2 = *(const ushort4*)(h_prev2 + (size_t)n * DIM + d4);
        acc.x -= gd * b2f(p2.x); acc.y -= gd * b2f(p2.y);
        acc.z -= gd * b2f(p2.z); acc.w -= gd * b2f(p2.w);
    }
    ushort4 o;
    o.x = f2b(acc.x); o.y = f2b(acc.y); o.z = f2b(acc.z); o.w = f2b(acc.w);
    *(ushort4*)(h_out + (size_t)n * DIM + d4) = o;
}

// ---------------------------------------------------------------------------
// Hop attention: wave w == head w (64 lanes == 64 head dims). bf16 in/out.
__global__ __launch_bounds__(256) void attn_kernel(const unsigned short* __restrict__ h0,
                                                   const unsigned short* __restrict__ h1,
                                                   const unsigned short* __restrict__ h2,
                                                   const unsigned short* __restrict__ h3,
                                                   const float* __restrict__ att_a,
                                                   unsigned short* __restrict__ out)
{
    const int n = blockIdx.x;
    const int t = threadIdx.x;
    const size_t i = (size_t)n * DIM + t;
    const float q = b2f(h0[i]);
    float hk[4];
    hk[0] = q; hk[1] = b2f(h1[i]); hk[2] = b2f(h2[i]); hk[3] = b2f(h3[i]);
    const float a = att_a[t];
    float sc[4];
#pragma unroll
    for (int k = 0; k < 4; ++k) {
        float v = tanhf(hk[k] + q) * a;
#pragma unroll
        for (int off = 32; off > 0; off >>= 1)
            v += __shfl_xor(v, off, 64);
        sc[k] = v;
    }
    const float mx = fmaxf(fmaxf(sc[0], sc[1]), fmaxf(sc[2], sc[3]));
    float ex[4], se = 0.f;
#pragma unroll
    for (int k = 0; k < 4; ++k) { ex[k] = __expf(sc[k] - mx); se += ex[k]; }
    const float inv = 1.f / se;
    float o = 0.f;
#pragma unroll
    for (int k = 0; k < 4; ++k) o += ex[k] * inv * hk[k];
    out[i] = f2b(o);
}

// ---------------------------------------------------------------------------
extern "C" void kernel_launch(void* const* d_in, const int* in_sizes, int n_in,
                              void* d_out, int out_size, void* d_ws, size_t ws_size,
                              hipStream_t stream)
{
    const float*    x         = (const float*)d_in[0];
    const unsigned* ei        = (const unsigned*)d_in[1];
    const float*    edge_attr = (const float*)d_in[2];
    const float*    W_x       = (const float*)d_in[3];
    const float*    W_e       = (const float*)d_in[4];
    const float*    att_a     = (const float*)d_in[5];
    const float*    W_ff1     = (const float*)d_in[6];
    const float*    W_ff2     = (const float*)d_in[7];

    char* ws = (char*)d_ws;
    size_t off = 0;
    auto alloc = [&](size_t bytes) -> void* {
        void* p = ws + off;
        off = (off + bytes + 255) & ~(size_t)255;
        return p;
    };
    int*   flag      = (int*)alloc(4);
    int*   src32     = (int*)alloc((size_t)N_EDGES * 4);
    int*   dst32     = (int*)alloc((size_t)N_EDGES * 4);
    int*   counts    = (int*)alloc((size_t)2 * N_NODES * 4);
    int*   fillc     = counts + N_NODES;
    int*   row_start = (int*)alloc((size_t)(N_NODES + 1) * 4);
    int*   csr_eid   = (int*)alloc((size_t)N_EDGES * 4);
    int*   csr_src   = (int*)alloc((size_t)N_EDGES * 4);
    unsigned short* h0b   = (unsigned short*)alloc((size_t)N_NODES * DIM * 2);
    unsigned short* h1b   = (unsigned short*)alloc((size_t)N_NODES * DIM * 2);
    unsigned short* h2b   = (unsigned short*)alloc((size_t)N_NODES * DIM * 2);
    unsigned short* h3b   = (unsigned short*)alloc((size_t)N_NODES * DIM * 2);
    unsigned short* e_bf  = (unsigned short*)alloc((size_t)N_EDGES * DIM * 2);
    unsigned short* attnb = (unsigned short*)alloc((size_t)N_NODES * DIM * 2);
    unsigned short* hidb  = (unsigned short*)alloc((size_t)N_NODES * FF_HIDDEN * 2);
    unsigned short* wxT   = (unsigned short*)alloc((size_t)DIM * DIM * 2);
    unsigned short* weT   = (unsigned short*)alloc((size_t)DIM * EDGE_DIM * 2);
    unsigned short* wff1T = (unsigned short*)alloc((size_t)FF_HIDDEN * DIM * 2);
    unsigned short* wff2T = (unsigned short*)alloc((size_t)DIM * FF_HIDDEN * 2);
    if (off > ws_size) return;

    const int egrid = (N_EDGES + 255) / 256;

    hipMemsetAsync(counts, 0, (size_t)2 * N_NODES * 4, stream);
    detect_kernel<<<1, 256, 0, stream>>>(ei, flag);
    convert_kernel<<<egrid, 256, 0, stream>>>(ei, flag, src32, dst32, counts);
    scan_kernel<<<1, 256, 0, stream>>>(counts, row_start);
    fill_kernel<<<egrid, 256, 0, stream>>>(src32, dst32, row_start, fillc, csr_eid, csr_src);

    wconv_kernel<<<(DIM * DIM + 255) / 256, 256, 0, stream>>>(W_x, wxT, DIM, DIM);
    wconv_kernel<<<(EDGE_DIM * DIM + 255) / 256, 256, 0, stream>>>(W_e, weT, EDGE_DIM, DIM);
    wconv_kernel<<<(DIM * FF_HIDDEN + 255) / 256, 256, 0, stream>>>(W_ff1, wff1T, DIM, FF_HIDDEN);
    wconv_kernel<<<(FF_HIDDEN * DIM + 255) / 256, 256, 0, stream>>>(W_ff2, wff2T, FF_HIDDEN, DIM);

    // h0 = x @ W_x -> bf16   (M=10000, K=256, N=256)
    wgemm<false, 0><<<dim3(157, 1), 256, 0, stream>>>(x, wxT, h0b,
        N_NODES, DIM, DIM, nullptr, nullptr);
    // e = edge_attr(gathered) @ W_e -> bf16, rows written sequentially in CSR order
    egemm_kernel<<<N_EDGES / 64, 256, 0, stream>>>(edge_attr, weT, e_bf, csr_eid);

    hop_kernel<<<N_NODES / 4, 256, 0, stream>>>(h0b, nullptr, e_bf, row_start, csr_src, h1b);
    hop_kernel<<<N_NODES / 4, 256, 0, stream>>>(h1b, h0b,     e_bf, row_start, csr_src, h2b);
    hop_kernel<<<N_NODES / 4, 256, 0, stream>>>(h2b, h1b,     e_bf, row_start, csr_src, h3b);

    attn_kernel<<<N_NODES, 256, 0, stream>>>(h0b, h1b, h2b, h3b, att_a, attnb);

    // hidden = relu(attn @ W_ff1) -> bf16   (M=10000, K=256, N=512)
    wgemm<true, 1><<<dim3(157, 2), 256, 0, stream>>>(attnb, wff1T, hidb,
        N_NODES, DIM, FF_HIDDEN, nullptr, nullptr);
    // d_out = x + relu(attn + hidden @ W_ff2)   (M=10000, K=512, N=256)
    wgemm<true, 2><<<dim3(157, 1), 256, 0, stream>>>(hidb, wff2T, d_out,
        N_NODES, FF_HIDDEN, DIM, attnb, x);
}